// Round 7
// baseline (320.401 us; speedup 1.0000x reference)
//
#include <hip/hip_runtime.h>

// Problem constants (fixed by the harness reference).
#define D_IN   1024
#define D_OUT  1024
#define KB_CNT (D_IN / 8)           // 128 K-blocks of 64 elements each
#define IMG_BYTES 16384             // one staged tile image: 128 rows x 64 bf16 = 16 KB
#define COL_TILES (D_OUT / 128)     // 8
#define BUFB 32768                  // gemm LDS buffer: A-tile only (256 rows x 64 k bf16)

typedef __attribute__((ext_vector_type(8))) short bf16x8;
typedef __attribute__((ext_vector_type(4))) float f32x4;
typedef __attribute__((ext_vector_type(4))) unsigned int u32x4;

typedef __attribute__((address_space(1))) unsigned int as1_u32;
typedef __attribute__((address_space(3))) unsigned int as3_u32;

__device__ __forceinline__ void gload_lds16(const void* g, void* l) {
  // async global->LDS, 16B per lane; LDS dest = wave-uniform base + lane*16
  __builtin_amdgcn_global_load_lds((const as1_u32*)(unsigned long long)g,
                                   (as3_u32*)(unsigned int)(unsigned long long)l,
                                   16, 0, 0);
}

__device__ __forceinline__ unsigned short f2bf(float f) {
  unsigned int u = __float_as_uint(f);
  u += 0x7fffu + ((u >> 16) & 1u);
  return (unsigned short)(u >> 16);
}

// Exact replication of the reference Cox-de Boor recursion (incl. EPS clamps
// and the xc==1 -> all-zero-basis behavior). b[0..6] = basis, returns silu.
__device__ __forceinline__ float basis_and_silu(float xv, float* b) {
  float xc = fminf(fmaxf(xv, -1.f), 1.f);
  const float G[11] = {-1.f, -1.f, -1.f, -1.f, -0.5f, 0.f, 0.5f, 1.f, 1.f, 1.f, 1.f};
  float t[10];
#pragma unroll
  for (int j = 0; j < 10; j++)
    t[j] = (xc >= G[j] && xc < G[j + 1]) ? 1.f : 0.f;
  t[9] += (xc == 1.f) ? 1.f : 0.f;
#pragma unroll
  for (int k = 1; k <= 3; k++) {
#pragma unroll
    for (int j = 0; j < 10 - k; j++) {
      float dl = G[j + k] - G[j];
      float il = 1.f / (dl < 1e-8f ? 1e-8f : dl);      // compile-time folded
      float dr = G[j + k + 1] - G[j + 1];
      float ir = 1.f / (dr < 1e-8f ? 1e-8f : dr);
      t[j] = (xc - G[j]) * il * t[j] + (G[j + k + 1] - xc) * ir * t[j + 1];
    }
  }
#pragma unroll
  for (int j = 0; j < 7; j++) b[j] = t[j];
  return xc / (1.f + __expf(-xc));
}

// ---------------------------------------------------------------------------
// prep: B'[k=i*8+b, o] as blocked swizzled images (tileC, kb) = bf16[128][64],
// byte_off = (col*128 + il*16) ^ ((col&7)<<4)
// ---------------------------------------------------------------------------
__global__ __launch_bounds__(256) void prep_kernel(const float* __restrict__ coeff,
                                                   const float* __restrict__ w_base,
                                                   char* __restrict__ bp) {
  int tid = blockIdx.x * 256 + threadIdx.x;   // tid = o*D_IN + i
  int o = tid >> 10;
  int i = tid & (D_IN - 1);

  float v[8];
#pragma unroll
  for (int b = 0; b < 7; b++) v[b] = coeff[(size_t)tid * 7 + b];
  v[7] = w_base[tid];

  union { unsigned short h[8]; u32x4 q; } u;
#pragma unroll
  for (int b = 0; b < 8; b++) u.h[b] = f2bf(v[b]);

  int tileC = o >> 7, cl = o & 127, kb = i >> 3, il = i & 7;
  size_t img = ((size_t)(tileC * KB_CNT + kb)) * IMG_BYTES;
  int off = (cl * 128 + il * 16) ^ ((cl & 7) << 4);
  *(u32x4*)(bp + img + off) = u.q;
}

// ---------------------------------------------------------------------------
// act: block = 8 rows x 128 i (16 images). x staged via LDS (coalesced reads);
// wave lane = il + 8*row_local -> each store = 64 lanes x 16B = 1 KB dense
// within one image (8-row stripe, swizzle is bijective inside the stripe).
// ---------------------------------------------------------------------------
__global__ __launch_bounds__(256) void act_kernel(const float* __restrict__ x,
                                                  char* __restrict__ ap) {
  __shared__ float xs[8][136];                // padded: conflict-light reads

  const int rg = blockIdx.x >> 3;             // row-group of 8 rows
  const int kg = blockIdx.x & 7;              // 16-kb group (128 i's)
  const int t = threadIdx.x;

  // cooperative coalesced load of x[8 rows][128 i]
#pragma unroll
  for (int rep = 0; rep < 4; rep++) {
    int idx = rep * 256 + t;                  // 0..1023
    int r = idx >> 7, ii = idx & 127;
    xs[r][ii] = x[((size_t)(rg * 8 + r) << 10) + kg * 128 + ii];
  }
  __syncthreads();

  const int il = t & 7;                       // i within kb
  const int rl = (t >> 3) & 7;                // row within group
  const int wv = t >> 6;                      // wave: 4 kb's each
  const int tile = rg >> 4;
  const int r = (rg & 15) * 8 + rl;           // row within 128-row image
  const int off = (r * 128 + il * 16) ^ (rl << 4);   // r&7 == rl

#pragma unroll
  for (int e = 0; e < 4; e++) {
    int kb_loc = wv * 4 + e;                  // 0..15 within group
    float xvv = xs[rl][kb_loc * 8 + il];
    float b[7];
    float s = basis_and_silu(xvv, b);
    union { unsigned short h[8]; u32x4 q; } u;
#pragma unroll
    for (int q2 = 0; q2 < 7; q2++) u.h[q2] = f2bf(b[q2]);
    u.h[7] = f2bf(s);
    int kb = kg * 16 + kb_loc;
    size_t img = ((size_t)(tile * KB_CNT + kb)) * IMG_BYTES;
    *(u32x4*)(ap + img + off) = u.q;
  }
}

// ---------------------------------------------------------------------------
// gemm8: 256x128 tile, 8 waves (4M x 2N, per-wave 64x64), BK=64.
// A: LDS 3-deep pipeline via global_load_lds (4 loads/K-tile, counted vmcnt).
// B: register double-buffer loaded straight from global images (L1/L2-hot),
//    removing 64KB/CU/K-tile from the LDS pipe. T1+T2+T5 retained.
// vmcnt ledger: per tile issue B(t+1)[8] then A-stage(t+2)[4]; one per-tile
// wait vmcnt(4) drains B(t+1)+A(t+1), leaves A(t+2); tail drains 0.
// ---------------------------------------------------------------------------
__global__ __launch_bounds__(512, 2) void gemm8_kernel(const char* __restrict__ ap,
                                                       const char* __restrict__ bp,
                                                       const float* __restrict__ bias,
                                                       float* __restrict__ out) {
  __shared__ __align__(16) char lds[3 * BUFB];   // 96 KB (A only)

  // T1: bijective XCD swizzle (m204)
  const int nwg = gridDim.x;
  const int orig = blockIdx.x;
  const int q = nwg >> 3, rq = nwg & 7;
  const int xcd = orig & 7, seq = orig >> 3;
  const int wg = (xcd < rq ? xcd * (q + 1) : rq * (q + 1) + (xcd - rq) * q) + seq;
  const int tileR = wg >> 3;        // 256-row tile (pair of images)
  const int tileC = wg & 7;

  const int tid = threadIdx.x;
  const int lane = tid & 63;
  const int w = tid >> 6;
  const int wm = w >> 1, wn = w & 1;

  const char* pa0 = ap + ((size_t)(tileR * 2 + 0) * KB_CNT) * IMG_BYTES + tid * 16;
  const char* pa1 = ap + ((size_t)(tileR * 2 + 1) * KB_CNT) * IMG_BYTES + tid * 16;
  const char* pbi = bp + ((size_t)tileC * KB_CNT) * IMG_BYTES;   // B image t=0
  char* lw = lds + w * 1024;        // wave-uniform staging chunk base

  f32x4 acc[4][4];
#pragma unroll
  for (int m = 0; m < 4; m++)
#pragma unroll
    for (int n = 0; n < 4; n++) acc[m][n] = (f32x4){0.f, 0.f, 0.f, 0.f};

  const int xm = (lane & 7) << 4;           // swizzle involution
  const int arow = wm * 64 + (lane & 15);
  const int bcol = wn * 64 + (lane & 15);
  const int kch = (lane >> 4) * 16;

  bf16x8 Bc[4][2], Bn[4][2];

  // ---- prologue: stageA(t0)[4], loadB(t0)[8], stageA(t1)[4] -> vmcnt(4) ----
  gload_lds16(pa0,        lw);
  gload_lds16(pa0 + 8192, lw + 8192);
  gload_lds16(pa1,        lw + 16384);
  gload_lds16(pa1 + 8192, lw + 24576);
  pa0 += IMG_BYTES; pa1 += IMG_BYTES;
#pragma unroll
  for (int n = 0; n < 4; ++n) {
    Bc[n][0] = *(const bf16x8*)(pbi + (((bcol + n * 16) * 128 + kch) ^ xm));
    Bc[n][1] = *(const bf16x8*)(pbi + (((bcol + n * 16) * 128 + 64 + kch) ^ xm));
  }
  gload_lds16(pa0,        lw + BUFB);
  gload_lds16(pa0 + 8192, lw + BUFB + 8192);
  gload_lds16(pa1,        lw + BUFB + 16384);
  gload_lds16(pa1 + 8192, lw + BUFB + 24576);
  pa0 += IMG_BYTES; pa1 += IMG_BYTES;
  const char* pbn = pbi + IMG_BYTES;        // B image of t+1
  asm volatile("s_waitcnt vmcnt(4)" ::: "memory");
  __builtin_amdgcn_s_barrier();

#define TILE_BODY(T, BCUR, BNXT, LB, SW)                                        \
  {                                                                             \
    const char* lb = (LB);                                                      \
    bf16x8 a0[2][2];                                                            \
    _Pragma("unroll")                                                           \
    for (int c = 0; c < 2; ++c) {                                               \
      a0[c][0] = *(const bf16x8*)(lb + (((arow + c * 16) * 128 + kch) ^ xm));   \
      a0[c][1] = *(const bf16x8*)(lb + (((arow + c * 16) * 128 + 64 + kch) ^ xm)); \
    }                                                                           \
    if ((T) + 1 < KB_CNT) {                                                     \
      _Pragma("unroll")                                                         \
      for (int n = 0; n < 4; ++n) {                                             \
        BNXT[n][0] = *(const bf16x8*)(pbn + (((bcol + n * 16) * 128 + kch) ^ xm)); \
        BNXT[n][1] = *(const bf16x8*)(pbn + (((bcol + n * 16) * 128 + 64 + kch) ^ xm)); \
      }                                                                         \
    }                                                                           \
    if ((T) + 2 < KB_CNT) {                                                     \
      gload_lds16(pa0,        (SW));                                            \
      gload_lds16(pa0 + 8192, (SW) + 8192);                                     \
    }                                                                           \
    __builtin_amdgcn_s_barrier();                                               \
    asm volatile("s_waitcnt lgkmcnt(0)" ::: "memory");                          \
    __builtin_amdgcn_s_setprio(1);                                              \
    _Pragma("unroll")                                                           \
    for (int c = 0; c < 2; ++c)                                                 \
      _Pragma("unroll")                                                         \
      for (int n = 0; n < 4; ++n) {                                             \
        acc[c][n] = __builtin_amdgcn_mfma_f32_16x16x32_bf16(a0[c][0], BCUR[n][0], acc[c][n], 0, 0, 0); \
        acc[c][n] = __builtin_amdgcn_mfma_f32_16x16x32_bf16(a0[c][1], BCUR[n][1], acc[c][n], 0, 0, 0); \
      }                                                                         \
    __builtin_amdgcn_s_setprio(0);                                              \
    __builtin_amdgcn_s_barrier();                                               \
    _Pragma("unroll")                                                           \
    for (int c = 0; c < 2; ++c) {                                               \
      a0[c][0] = *(const bf16x8*)(lb + (((arow + (c + 2) * 16) * 128 + kch) ^ xm)); \
      a0[c][1] = *(const bf16x8*)(lb + (((arow + (c + 2) * 16) * 128 + 64 + kch) ^ xm)); \
    }                                                                           \
    if ((T) + 2 < KB_CNT) {                                                     \
      gload_lds16(pa1,        (SW) + 16384);                                    \
      gload_lds16(pa1 + 8192, (SW) + 24576);                                    \
      pa0 += IMG_BYTES; pa1 += IMG_BYTES;                                       \
    }                                                                           \
    pbn += IMG_BYTES;                                                           \
    if ((T) < KB_CNT - 2) { asm volatile("s_waitcnt vmcnt(4)" ::: "memory"); }  \
    else                  { asm volatile("s_waitcnt vmcnt(0)" ::: "memory"); }  \
    __builtin_amdgcn_s_barrier();                                               \
    asm volatile("s_waitcnt lgkmcnt(0)" ::: "memory");                          \
    __builtin_amdgcn_s_setprio(1);                                              \
    _Pragma("unroll")                                                           \
    for (int c = 0; c < 2; ++c)                                                 \
      _Pragma("unroll")                                                         \
      for (int n = 0; n < 4; ++n) {                                             \
        acc[c + 2][n] = __builtin_amdgcn_mfma_f32_16x16x32_bf16(a0[c][0], BCUR[n][0], acc[c + 2][n], 0, 0, 0); \
        acc[c + 2][n] = __builtin_amdgcn_mfma_f32_16x16x32_bf16(a0[c][1], BCUR[n][1], acc[c + 2][n], 0, 0, 0); \
      }                                                                         \
    __builtin_amdgcn_s_setprio(0);                                              \
    __builtin_amdgcn_s_barrier();                                               \
  }

  int bsel = 0;
  for (int t = 0; t < KB_CNT; t += 2) {
    const int s0 = bsel + 2 > 2 ? bsel - 1 : bsel + 2;     // (bsel+2)%3
    TILE_BODY(t, Bc, Bn, lds + bsel * BUFB, lw + s0 * BUFB);
    const int b1 = bsel + 1 > 2 ? 0 : bsel + 1;
    const int s1 = b1 + 2 > 2 ? b1 - 1 : b1 + 2;
    TILE_BODY(t + 1, Bn, Bc, lds + b1 * BUFB, lw + s1 * BUFB);
    bsel = b1 + 1 > 2 ? 0 : b1 + 1;
  }
#undef TILE_BODY

  // epilogue: C/D layout col=lane&15, row=(lane>>4)*4+j
  const int r0 = tileR * 256 + wm * 64 + ((lane >> 4) * 4);
  const int c0 = tileC * 128 + wn * 64 + (lane & 15);
#pragma unroll
  for (int m = 0; m < 4; m++) {
#pragma unroll
    for (int n = 0; n < 4; n++) {
      int c = c0 + n * 16;
      float bv = bias[c];
#pragma unroll
      for (int j = 0; j < 4; j++) {
        int rr = r0 + m * 16 + j;
        out[(size_t)rr * D_OUT + c] = acc[m][n][j] + bv;
      }
    }
  }
}

// ---------------------------------------------------------------------------
// naive fallback (tiny ws only): fp32 VALU, no workspace. Correct, slow.
// ---------------------------------------------------------------------------
__global__ __launch_bounds__(256) void naive_kernel(const float* __restrict__ x,
                                                    const float* __restrict__ coeff,
                                                    const float* __restrict__ w_base,
                                                    const float* __restrict__ bias,
                                                    float* __restrict__ out) {
  __shared__ float sb[D_IN][8];
  const int n = blockIdx.x >> 2;
  const int o = (blockIdx.x & 3) * 256 + threadIdx.x;

  for (int i = threadIdx.x; i < D_IN; i += 256) {
    float b[7];
    float s = basis_and_silu(x[(size_t)n * D_IN + i], b);
#pragma unroll
    for (int qd = 0; qd < 7; qd++) sb[i][qd] = b[qd];
    sb[i][7] = s;
  }
  __syncthreads();

  float acc = bias[o];
  for (int i = 0; i < D_IN; i++) {
    const float* cp = coeff + ((size_t)o * D_IN + i) * 7;
    float p = sb[i][7] * w_base[(size_t)o * D_IN + i];
#pragma unroll
    for (int qd = 0; qd < 7; qd++) p += sb[i][qd] * cp[qd];
    acc += p;
  }
  out[(size_t)n * D_OUT + o] = acc;
}

// ---------------------------------------------------------------------------
extern "C" void kernel_launch(void* const* d_in, const int* in_sizes, int n_in,
                              void* d_out, int out_size, void* d_ws, size_t ws_size,
                              hipStream_t stream) {
  const float* x      = (const float*)d_in[0];
  const float* coeff  = (const float*)d_in[1];
  const float* w_base = (const float*)d_in[2];
  const float* bias   = (const float*)d_in[3];
  float* out = (float*)d_out;

  const int n_rows = in_sizes[0] / D_IN;      // 8192
  const int row_tiles = n_rows / 128;         // 64

  const size_t bp_bytes = (size_t)COL_TILES * KB_CNT * IMG_BYTES;   // 16 MB
  const size_t tile_bytes = (size_t)KB_CNT * IMG_BYTES;             // 2 MB / row-tile

  if (ws_size < bp_bytes + 2 * tile_bytes) {
    naive_kernel<<<n_rows * 4, 256, 0, stream>>>(x, coeff, w_base, bias, out);
    return;
  }

  char* bpw = (char*)d_ws;
  char* apb = bpw + bp_bytes;
  size_t avail = ws_size - bp_bytes;
  int chunk_tiles = (int)(avail / tile_bytes) & ~1;   // even: gemm tiles pairs
  if (chunk_tiles > row_tiles) chunk_tiles = row_tiles;

  prep_kernel<<<(D_OUT * D_IN) / 256, 256, 0, stream>>>(coeff, w_base, bpw);

  for (int t0 = 0; t0 < row_tiles; t0 += chunk_tiles) {
    int nt = (row_tiles - t0 < chunk_tiles) ? (row_tiles - t0) : chunk_tiles;
    // act: blocks = (nt*128 rows / 8) * 8 kb-groups
    act_kernel<<<nt * 16 * 8, 256, 0, stream>>>(x + (size_t)t0 * 128 * D_IN, apb);
    gemm8_kernel<<<(nt / 2) * COL_TILES, 512, 0, stream>>>(
        apb, bpw, bias, out + (size_t)t0 * 128 * D_OUT);
  }
}